// Round 4
// baseline (229.183 us; speedup 1.0000x reference)
//
#include <hip/hip_runtime.h>
#include <hip/hip_bf16.h>
#include <stdint.h>

#define BB 2
#define SS 2048
#define HQ 32
#define HKV 8
#define DD 128
#define WIN 512

typedef __bf16 bf16x8 __attribute__((ext_vector_type(8)));
typedef __bf16 bf16x4 __attribute__((ext_vector_type(4)));
typedef float f32x4 __attribute__((ext_vector_type(4)));

__device__ __forceinline__ bf16x8 cvt8(float4 a, float4 b, float s) {
  bf16x8 r;
  r[0] = (__bf16)(a.x * s); r[1] = (__bf16)(a.y * s);
  r[2] = (__bf16)(a.z * s); r[3] = (__bf16)(a.w * s);
  r[4] = (__bf16)(b.x * s); r[5] = (__bf16)(b.y * s);
  r[6] = (__bf16)(b.z * s); r[7] = (__bf16)(b.w * s);
  return r;
}

// grid: (S/64, HKV, B), block 512 = 8 waves.
// wave = (wq = wave&3 : 16-row quarter, wh = wave>>2 : head pair)
__global__ __launch_bounds__(512, 4) void attn_kernel(
    const float* __restrict__ qg, const float* __restrict__ kg,
    const float* __restrict__ vg, const float* __restrict__ sinkg,
    float* __restrict__ outg)
{
  const int qtile = blockIdx.x, hkv = blockIdx.y, b = blockIdx.z;
  const int qb = qtile * 64;
  const int tid = threadIdx.x;
  const int wave = tid >> 6, lane = tid & 63;
  const int wq = wave & 3, wh = wave >> 2;
  const int g = lane >> 4, c = lane & 15;
  const int hq0 = (hkv << 2) + (wh << 1);

  __shared__ __bf16 Kl[32 * 128];    // 256B rows, XOR-swizzled by (row&7)<<4
  __shared__ __bf16 Vt[128][40];     // V transposed: Vt[d][kv], 80B rows
  __shared__ __bf16 Pl[16][16 * 40]; // [wave*2+head] P buffers, 80B rows

  const float LOG2E = 1.4426950408889634f;
  const float scale = 0.08838834764831845f * LOG2E;
  const float THR = 12.0f; // defer-max threshold (exp2 domain)
  const int qw = qb + wq * 16;
  const int qrow = qw + c;

  // Q fragments (B-operand of swapped QK^T), both heads, pre-scaled
  bf16x8 qf[2][4];
  #pragma unroll
  for (int hh = 0; hh < 2; ++hh) {
    const float* qp = qg + (((size_t)b * SS + qrow) * HQ + hq0 + hh) * DD;
    #pragma unroll
    for (int ch = 0; ch < 4; ++ch) {
      float4 a = *(const float4*)(qp + ch * 32 + g * 8);
      float4 b2 = *(const float4*)(qp + ch * 32 + g * 8 + 4);
      qf[hh][ch] = cvt8(a, b2, scale);
    }
  }

  const float sk[2] = {sinkg[hq0] * LOG2E, sinkg[hq0 + 1] * LOG2E};

  float mm[2] = {-1e30f, -1e30f}, ll[2] = {0.f, 0.f};
  f32x4 acc[2][8];
  #pragma unroll
  for (int hh = 0; hh < 2; ++hh)
    #pragma unroll
    for (int i = 0; i < 8; ++i) acc[hh][i] = (f32x4){0.f, 0.f, 0.f, 0.f};

  const int t0 = (qb > (WIN - 1) ? (qb - (WIN - 1)) : 0) >> 5;
  const int t1 = (qb + 63) >> 5;

  // staging thread roles
  const int krow = tid >> 4, kh = tid & 15;
  const int vd = tid & 127, vc4 = tid >> 7;

  auto issue = [&](int kb, float4& ka, float4& ka2, float* vr) {
    const float* kp = kg + (((size_t)b * SS + kb + krow) * HKV + hkv) * DD + kh * 8;
    ka = *(const float4*)(kp);
    ka2 = *(const float4*)(kp + 4);
    const float* vp = vg + (((size_t)b * SS + kb + vc4 * 8) * HKV + hkv) * DD + vd;
    #pragma unroll
    for (int j = 0; j < 8; ++j) vr[j] = vp[(size_t)j * (HKV * DD)];
  };
  auto commit = [&](const float4& ka, const float4& ka2, const float* vr) {
    *(bf16x8*)((char*)Kl + krow * 256 + ((kh * 16) ^ ((krow & 7) << 4))) = cvt8(ka, ka2, 1.f);
    bf16x8 w;
    #pragma unroll
    for (int j = 0; j < 8; ++j) w[j] = (__bf16)vr[j];
    *(bf16x8*)(&Vt[vd][vc4 * 8]) = w;
  };

  float4 ka, ka2; float vr[8];
  issue(t0 << 5, ka, ka2, vr);
  commit(ka, ka2, vr);
  __syncthreads();

  for (int t = t0; t <= t1; ++t) {
    const int kb = t << 5;
    const bool hn = (t < t1);
    if (hn) issue((t + 1) << 5, ka, ka2, vr); // prefetch next tile into regs

    const bool active = !(kb > qw + 15 || kb + 31 < qw - (WIN - 1));
    if (active) {
      // ---- QK^T (swapped) both heads: S^T[k][q] ----
      f32x4 sc0[2] = {{0.f,0.f,0.f,0.f},{0.f,0.f,0.f,0.f}};
      f32x4 sc1[2] = {{0.f,0.f,0.f,0.f},{0.f,0.f,0.f,0.f}};
      #pragma unroll
      for (int ch = 0; ch < 4; ++ch) {
        const int off = (ch * 64 + g * 16) ^ ((c & 7) << 4);
        bf16x8 a0 = *(bf16x8*)((char*)Kl + c * 256 + off);
        bf16x8 a1 = *(bf16x8*)((char*)Kl + (16 + c) * 256 + off);
        sc0[0] = __builtin_amdgcn_mfma_f32_16x16x32_bf16(a0, qf[0][ch], sc0[0], 0, 0, 0);
        sc1[0] = __builtin_amdgcn_mfma_f32_16x16x32_bf16(a1, qf[0][ch], sc1[0], 0, 0, 0);
        sc0[1] = __builtin_amdgcn_mfma_f32_16x16x32_bf16(a0, qf[1][ch], sc0[1], 0, 0, 0);
        sc1[1] = __builtin_amdgcn_mfma_f32_16x16x32_bf16(a1, qf[1][ch], sc1[1], 0, 0, 0);
      }

      // ---- shared band mask (head-independent) ----
      bool ok[8];
      #pragma unroll
      for (int t2 = 0; t2 < 2; ++t2)
        #pragma unroll
        for (int r = 0; r < 4; ++r) {
          const int kk = kb + t2 * 16 + g * 4 + r;
          ok[t2 * 4 + r] = (kk <= qrow) && (qrow - kk < WIN);
        }

      // ---- per-head online softmax (exp2 domain, defer-max) ----
      #pragma unroll
      for (int hh = 0; hh < 2; ++hh) {
        float p[8];
        float tmax = -1e30f;
        #pragma unroll
        for (int t2 = 0; t2 < 2; ++t2)
          #pragma unroll
          for (int r = 0; r < 4; ++r) {
            float sv = t2 ? sc1[hh][r] : sc0[hh][r];
            sv = ok[t2 * 4 + r] ? sv : -1e30f;
            p[t2 * 4 + r] = sv;
            tmax = fmaxf(tmax, sv);
          }
        tmax = fmaxf(tmax, __shfl_xor(tmax, 16));
        tmax = fmaxf(tmax, __shfl_xor(tmax, 32));

        const bool resc = __any(tmax > mm[hh] + THR);
        const float mnew = resc ? fmaxf(mm[hh], tmax) : mm[hh];
        float tsum = 0.f;
        #pragma unroll
        for (int j = 0; j < 8; ++j) {
          const float e = (p[j] > -9e29f) ? exp2f(p[j] - mnew) : 0.f;
          p[j] = e;
          tsum += e;
        }
        tsum += __shfl_xor(tsum, 16);
        tsum += __shfl_xor(tsum, 32);

        if (resc) {
          const float scl = exp2f(mm[hh] - mnew);
          ll[hh] = ll[hh] * scl + tsum;
          const float f0 = __shfl(scl, g * 4 + 0), f1 = __shfl(scl, g * 4 + 1);
          const float f2 = __shfl(scl, g * 4 + 2), f3 = __shfl(scl, g * 4 + 3);
          #pragma unroll
          for (int dt = 0; dt < 8; ++dt) {
            acc[hh][dt][0] *= f0; acc[hh][dt][1] *= f1;
            acc[hh][dt][2] *= f2; acc[hh][dt][3] *= f3;
          }
          mm[hh] = mnew;
        } else {
          ll[hh] += tsum;
        }

        char* pb = (char*)(&Pl[wave * 2 + hh][0]) + c * 80;
        #pragma unroll
        for (int t2 = 0; t2 < 2; ++t2) {
          bf16x4 w;
          w[0] = (__bf16)p[t2 * 4 + 0]; w[1] = (__bf16)p[t2 * 4 + 1];
          w[2] = (__bf16)p[t2 * 4 + 2]; w[3] = (__bf16)p[t2 * 4 + 3];
          *(bf16x4*)(pb + t2 * 32 + g * 8) = w;
        }
      }

      // ---- PV: shared V reads feed both heads ----
      bf16x8 pa0 = *(bf16x8*)((char*)(&Pl[wave * 2 + 0][0]) + c * 80 + g * 16);
      bf16x8 pa1 = *(bf16x8*)((char*)(&Pl[wave * 2 + 1][0]) + c * 80 + g * 16);
      #pragma unroll
      for (int dt = 0; dt < 8; ++dt) {
        bf16x8 vv = *(bf16x8*)(&Vt[dt * 16 + c][g * 8]);
        acc[0][dt] = __builtin_amdgcn_mfma_f32_16x16x32_bf16(pa0, vv, acc[0][dt], 0, 0, 0);
        acc[1][dt] = __builtin_amdgcn_mfma_f32_16x16x32_bf16(pa1, vv, acc[1][dt], 0, 0, 0);
      }
    }

    if (hn) {
      __syncthreads();           // all waves done reading LDS tile t
      commit(ka, ka2, vr);       // vmcnt wait lands here (compiler)
      __syncthreads();           // tile t+1 visible
    }
  }

  // ---- epilogue: sink + normalize, write out (both heads) ----
  #pragma unroll
  for (int hh = 0; hh < 2; ++hh) {
    const float Mf = fmaxf(mm[hh], sk[hh]);
    const float ex = exp2f(mm[hh] - Mf);
    const float denom = ll[hh] * ex + exp2f(sk[hh] - Mf);
    const float fac = ex / denom;
    const float f0 = __shfl(fac, g * 4 + 0), f1 = __shfl(fac, g * 4 + 1);
    const float f2 = __shfl(fac, g * 4 + 2), f3 = __shfl(fac, g * 4 + 3);
    const float fr[4] = {f0, f1, f2, f3};
    #pragma unroll
    for (int dt = 0; dt < 8; ++dt) {
      #pragma unroll
      for (int r = 0; r < 4; ++r) {
        const int row = qw + g * 4 + r;
        outg[(((size_t)b * SS + row) * HQ + hq0 + hh) * DD + dt * 16 + c] = acc[hh][dt][r] * fr[r];
      }
    }
  }
}

// ---- cache path: inverse-map single-pass fill ----
__global__ void build_inv(const int* __restrict__ ids, int* __restrict__ inv,
                          int npages, int nslots) {
  const int i = threadIdx.x;
  if (i < npages) inv[i] = -1;
  __syncthreads();
  if (i < nslots) inv[ids[i]] = i;
}

// grid (npages, 2): fill one page-half from K/V (if mapped) else from cache_in
__global__ void page_fill(const float* __restrict__ kg, const float* __restrict__ vg,
                          const float* __restrict__ cache_in, const int* __restrict__ inv,
                          float* __restrict__ cache) {
  const int page = blockIdx.x, half = blockIdx.y;
  const int slot = inv[page];
  float4* d4 = (float4*)cache;
  const size_t dbase = (((size_t)page * 2 + half) * 8) * 1024;
  if (slot >= 0) {
    const int b = slot >> 6, blk = slot & 63;
    const float4* s4 = (const float4*)(half ? vg : kg);
    for (int f = threadIdx.x; f < 8192; f += blockDim.x) {
      const int d = f & 31, s = (f >> 5) & 31, h = f >> 10;
      d4[dbase + (size_t)h * 1024 + s * 32 + d] =
          s4[(((size_t)b * SS + blk * 32 + s) * 8 + h) * 32 + d];
    }
  } else {
    const float4* s4 = (const float4*)cache_in;
    for (int f = threadIdx.x; f < 8192; f += blockDim.x)
      d4[dbase + f] = s4[dbase + f];
  }
}

// fallback (no workspace): copy + scatter
__global__ void cache_copy(const float* __restrict__ src, float* __restrict__ dst, int n4) {
  const float4* s = (const float4*)src;
  float4* d = (float4*)dst;
  for (int i = blockIdx.x * blockDim.x + threadIdx.x; i < n4; i += gridDim.x * blockDim.x)
    d[i] = s[i];
}
__global__ void cache_scatter(const float* __restrict__ kg, const float* __restrict__ vg,
                              const int* __restrict__ ids, float* __restrict__ cache) {
  const int slot = blockIdx.x;
  const int half = blockIdx.y;
  const int b = slot >> 6, blk = slot & 63;
  const int page = ids[slot];
  const float4* s4 = (const float4*)(half ? vg : kg);
  float4* d4 = (float4*)cache;
  for (int f = threadIdx.x; f < 8192; f += blockDim.x) {
    const int d = f & 31, s = (f >> 5) & 31, h = f >> 10;
    d4[(((size_t)page * 2 + half) * 8 + h) * 1024 + s * 32 + d] =
        s4[(((size_t)b * SS + blk * 32 + s) * 8 + h) * 32 + d];
  }
}

extern "C" void kernel_launch(void* const* d_in, const int* in_sizes, int n_in,
                              void* d_out, int out_size, void* d_ws, size_t ws_size,
                              hipStream_t stream) {
  const float* q = (const float*)d_in[0];
  const float* k = (const float*)d_in[1];
  const float* v = (const float*)d_in[2];
  const float* cache_in = (const float*)d_in[3];
  const int* ids = (const int*)d_in[4];
  const float* sink = (const float*)d_in[5];
  float* out = (float*)d_out;
  float* cache_out = out + (size_t)BB * SS * HQ * DD; // 16,777,216

  const int nslots = in_sizes[4];                 // B * nb = 128
  const int npages = in_sizes[3] / (2 * HKV * 32 * DD); // 128

  if (ws_size >= (size_t)npages * sizeof(int) && npages <= 1024) {
    int* inv = (int*)d_ws;
    build_inv<<<1, 1024, 0, stream>>>(ids, inv, npages, nslots);
    page_fill<<<dim3(npages, 2), 256, 0, stream>>>(k, v, cache_in, inv, cache_out);
  } else {
    cache_copy<<<4096, 256, 0, stream>>>(cache_in, cache_out, (BB * SS * HKV * DD * 2) / 4);
    cache_scatter<<<dim3(BB * 64, 2), 256, 0, stream>>>(k, v, ids, cache_out);
  }
  attn_kernel<<<dim3(SS / 64, HKV, BB), 512, 0, stream>>>(q, k, v, sink, out);
}

// Round 5
// 109.861 us; speedup vs baseline: 2.0861x; 2.0861x over previous
//
#include <hip/hip_runtime.h>
#include <hip/hip_bf16.h>
#include <stdint.h>

#define BB 2
#define SS 2048
#define HQ 32
#define HKV 8
#define DD 128
#define WIN 512

typedef __bf16 bf16x8 __attribute__((ext_vector_type(8)));
typedef __bf16 bf16x4 __attribute__((ext_vector_type(4)));
typedef float f32x4 __attribute__((ext_vector_type(4)));

__device__ __forceinline__ bf16x8 cvt8(float4 a, float4 b, float s) {
  bf16x8 r;
  r[0] = (__bf16)(a.x * s); r[1] = (__bf16)(a.y * s);
  r[2] = (__bf16)(a.z * s); r[3] = (__bf16)(a.w * s);
  r[4] = (__bf16)(b.x * s); r[5] = (__bf16)(b.y * s);
  r[6] = (__bf16)(b.z * s); r[7] = (__bf16)(b.w * s);
  return r;
}

// 1D grid 512 blocks (XCD-swizzled), block 512 = 8 waves.
// wave = (wq = wave&3 : 16-row quarter, wh = wave>>2 : head pair)
__global__ __launch_bounds__(512, 2) void attn_kernel(
    const float* __restrict__ qg, const float* __restrict__ kg,
    const float* __restrict__ vg, const float* __restrict__ sinkg,
    float* __restrict__ outg)
{
  // XCD-aware bijective swizzle: 512 blocks / 8 XCDs = 64 per XCD,
  // giving each XCD two full (b,hkv) K/V working sets (4 MB = its L2).
  const int sid = (blockIdx.x & 7) * 64 + (blockIdx.x >> 3);
  const int qtile = sid & 31, hkv = (sid >> 5) & 7, b = sid >> 8;
  const int qb = qtile * 64;
  const int tid = threadIdx.x;
  const int wave = tid >> 6, lane = tid & 63;
  const int wq = wave & 3, wh = wave >> 2;
  const int g = lane >> 4, c = lane & 15;
  const int hq0 = (hkv << 2) + (wh << 1);

  __shared__ __bf16 Kl[2][32 * 128];  // dbuf; 256B rows, XOR-swizzled (row&7)<<4
  __shared__ __bf16 Vt[2][128 * 40];  // dbuf; V transposed [d][kv], 80B rows
  __shared__ __bf16 Pl[16][16 * 40];  // [wave*2+head] P buffers, 80B rows

  const float LOG2E = 1.4426950408889634f;
  const float scale = 0.08838834764831845f * LOG2E;
  const float THR = 12.0f; // defer-max threshold (log2 domain)
  const int qw = qb + wq * 16;
  const int qrow = qw + c;

  // Q fragments (B-operand of swapped QK^T), both heads, pre-scaled
  bf16x8 qf[2][4];
  #pragma unroll
  for (int hh = 0; hh < 2; ++hh) {
    const float* qp = qg + (((size_t)b * SS + qrow) * HQ + hq0 + hh) * DD;
    #pragma unroll
    for (int ch = 0; ch < 4; ++ch) {
      float4 a = *(const float4*)(qp + ch * 32 + g * 8);
      float4 b2 = *(const float4*)(qp + ch * 32 + g * 8 + 4);
      qf[hh][ch] = cvt8(a, b2, scale);
    }
  }

  const float sk[2] = {sinkg[hq0] * LOG2E, sinkg[hq0 + 1] * LOG2E};

  float mm[2] = {-1e30f, -1e30f}, ll[2] = {0.f, 0.f};
  f32x4 acc[2][8];
  #pragma unroll
  for (int hh = 0; hh < 2; ++hh)
    #pragma unroll
    for (int i = 0; i < 8; ++i) acc[hh][i] = (f32x4){0.f, 0.f, 0.f, 0.f};

  const int t0 = (qb > (WIN - 1) ? (qb - (WIN - 1)) : 0) >> 5;
  const int t1 = (qb + 63) >> 5;

  // staging thread roles + bump pointers (no per-iter 64-bit rederivation)
  const int krow = tid >> 4, kh = tid & 15;
  const int vd = tid & 127, vc4 = tid >> 7;
  const int KSTEP = 32 * HKV * DD; // floats per k-tile
  const float* kp = kg + (((size_t)b * SS + (t0 << 5) + krow) * HKV + hkv) * DD + kh * 8;
  const float* vp = vg + (((size_t)b * SS + (t0 << 5) + vc4 * 8) * HKV + hkv) * DD + vd;

  float4 ka, ka2; float vr[8];
  auto issue = [&]() {
    ka = *(const float4*)(kp);
    ka2 = *(const float4*)(kp + 4);
    #pragma unroll
    for (int j = 0; j < 8; ++j) vr[j] = vp[(size_t)j * (HKV * DD)];
  };
  auto commit = [&](int buf) {
    *(bf16x8*)((char*)(&Kl[buf][0]) + krow * 256 + ((kh * 16) ^ ((krow & 7) << 4))) =
        cvt8(ka, ka2, 1.f);
    bf16x8 w;
    #pragma unroll
    for (int j = 0; j < 8; ++j) w[j] = (__bf16)vr[j];
    *(bf16x8*)(&Vt[buf][vd * 40 + vc4 * 8]) = w;
  };

  issue();
  commit(0);
  __syncthreads();
  int cur = 0;

  for (int t = t0; t <= t1; ++t) {
    const int kb = t << 5;
    const bool hn = (t < t1);
    if (hn) { kp += KSTEP; vp += KSTEP; issue(); } // loads for t+1 in flight

    const bool active = !(kb > qw + 15 || kb + 31 < qw - (WIN - 1));
    if (active) {
      const __bf16* Ks = &Kl[cur][0];
      const __bf16* Vs = &Vt[cur][0];

      // ---- QK^T (swapped) both heads: S^T[k][q] ----
      f32x4 sc0[2] = {{0.f,0.f,0.f,0.f},{0.f,0.f,0.f,0.f}};
      f32x4 sc1[2] = {{0.f,0.f,0.f,0.f},{0.f,0.f,0.f,0.f}};
      #pragma unroll
      for (int ch = 0; ch < 4; ++ch) {
        const int off = (ch * 64 + g * 16) ^ ((c & 7) << 4);
        bf16x8 a0 = *(const bf16x8*)((const char*)Ks + c * 256 + off);
        bf16x8 a1 = *(const bf16x8*)((const char*)Ks + (16 + c) * 256 + off);
        sc0[0] = __builtin_amdgcn_mfma_f32_16x16x32_bf16(a0, qf[0][ch], sc0[0], 0, 0, 0);
        sc1[0] = __builtin_amdgcn_mfma_f32_16x16x32_bf16(a1, qf[0][ch], sc1[0], 0, 0, 0);
        sc0[1] = __builtin_amdgcn_mfma_f32_16x16x32_bf16(a0, qf[1][ch], sc0[1], 0, 0, 0);
        sc1[1] = __builtin_amdgcn_mfma_f32_16x16x32_bf16(a1, qf[1][ch], sc1[1], 0, 0, 0);
      }

      // interior tiles need no masking at all (~15 of 17 per wave)
      const bool noMask = (kb + 31 <= qw) && (kb >= qw - (WIN - 16));

      #pragma unroll
      for (int hh = 0; hh < 2; ++hh) {
        float p[8];
        #pragma unroll
        for (int r = 0; r < 4; ++r) { p[r] = sc0[hh][r]; p[4 + r] = sc1[hh][r]; }
        if (!noMask) {
          #pragma unroll
          for (int t2 = 0; t2 < 2; ++t2)
            #pragma unroll
            for (int r = 0; r < 4; ++r) {
              const int kk = kb + t2 * 16 + g * 4 + r;
              const bool ok = (kk <= qrow) && (qrow - kk < WIN);
              p[t2 * 4 + r] = ok ? p[t2 * 4 + r] : -1e30f;
            }
        }
        float tmax = p[0];
        #pragma unroll
        for (int j = 1; j < 8; ++j) tmax = fmaxf(tmax, p[j]);
        tmax = fmaxf(tmax, __shfl_xor(tmax, 16));
        tmax = fmaxf(tmax, __shfl_xor(tmax, 32));

        const bool resc = __any(tmax > mm[hh] + THR);
        const float mnew = resc ? fmaxf(mm[hh], tmax) : mm[hh];
        float tsum = 0.f;
        if (noMask) {
          #pragma unroll
          for (int j = 0; j < 8; ++j) { p[j] = exp2f(p[j] - mnew); tsum += p[j]; }
        } else {
          #pragma unroll
          for (int j = 0; j < 8; ++j) {
            const float e = (p[j] > -9e29f) ? exp2f(p[j] - mnew) : 0.f;
            p[j] = e; tsum += e;
          }
        }
        tsum += __shfl_xor(tsum, 16);
        tsum += __shfl_xor(tsum, 32);

        if (resc) {
          const float scl = exp2f(mm[hh] - mnew);
          ll[hh] = ll[hh] * scl + tsum;
          const float f0 = __shfl(scl, g * 4 + 0), f1 = __shfl(scl, g * 4 + 1);
          const float f2 = __shfl(scl, g * 4 + 2), f3 = __shfl(scl, g * 4 + 3);
          #pragma unroll
          for (int dt = 0; dt < 8; ++dt) {
            acc[hh][dt][0] *= f0; acc[hh][dt][1] *= f1;
            acc[hh][dt][2] *= f2; acc[hh][dt][3] *= f3;
          }
          mm[hh] = mnew;
        } else {
          ll[hh] += tsum;
        }

        char* pb = (char*)(&Pl[wave * 2 + hh][0]) + c * 80;
        #pragma unroll
        for (int t2 = 0; t2 < 2; ++t2) {
          bf16x4 w;
          w[0] = (__bf16)p[t2 * 4 + 0]; w[1] = (__bf16)p[t2 * 4 + 1];
          w[2] = (__bf16)p[t2 * 4 + 2]; w[3] = (__bf16)p[t2 * 4 + 3];
          *(bf16x4*)(pb + t2 * 32 + g * 8) = w;
        }
      }

      // ---- PV: shared V reads feed both heads ----
      bf16x8 pa0 = *(bf16x8*)((char*)(&Pl[wave * 2 + 0][0]) + c * 80 + g * 16);
      bf16x8 pa1 = *(bf16x8*)((char*)(&Pl[wave * 2 + 1][0]) + c * 80 + g * 16);
      #pragma unroll
      for (int dt = 0; dt < 8; ++dt) {
        bf16x8 vv = *(const bf16x8*)(Vs + (dt * 16 + c) * 40 + g * 8);
        acc[0][dt] = __builtin_amdgcn_mfma_f32_16x16x32_bf16(pa0, vv, acc[0][dt], 0, 0, 0);
        acc[1][dt] = __builtin_amdgcn_mfma_f32_16x16x32_bf16(pa1, vv, acc[1][dt], 0, 0, 0);
      }
    }

    if (hn) {
      commit(cur ^ 1);   // write OTHER buffer: no WAR with tile-t readers
      __syncthreads();   // one barrier per tile
      cur ^= 1;
    }
  }

  // ---- epilogue: sink + normalize, write out (both heads) ----
  #pragma unroll
  for (int hh = 0; hh < 2; ++hh) {
    const float Mf = fmaxf(mm[hh], sk[hh]);
    const float ex = exp2f(mm[hh] - Mf);
    const float denom = ll[hh] * ex + exp2f(sk[hh] - Mf);
    const float fac = ex / denom;
    const float f0 = __shfl(fac, g * 4 + 0), f1 = __shfl(fac, g * 4 + 1);
    const float f2 = __shfl(fac, g * 4 + 2), f3 = __shfl(fac, g * 4 + 3);
    const float fr[4] = {f0, f1, f2, f3};
    #pragma unroll
    for (int dt = 0; dt < 8; ++dt) {
      #pragma unroll
      for (int r = 0; r < 4; ++r) {
        const int row = qw + g * 4 + r;
        outg[(((size_t)b * SS + row) * HQ + hq0 + hh) * DD + dt * 16 + c] = acc[hh][dt][r] * fr[r];
      }
    }
  }
}

// ---- cache path: inverse-map single-pass fill ----
__global__ void build_inv(const int* __restrict__ ids, int* __restrict__ inv,
                          int npages, int nslots) {
  const int i = threadIdx.x;
  if (i < npages) inv[i] = -1;
  __syncthreads();
  if (i < nslots) inv[ids[i]] = i;
}

__global__ void page_fill(const float* __restrict__ kg, const float* __restrict__ vg,
                          const float* __restrict__ cache_in, const int* __restrict__ inv,
                          float* __restrict__ cache) {
  const int page = blockIdx.x, half = blockIdx.y;
  const int slot = inv[page];
  float4* d4 = (float4*)cache;
  const size_t dbase = (((size_t)page * 2 + half) * 8) * 1024;
  if (slot >= 0) {
    const int b = slot >> 6, blk = slot & 63;
    const float4* s4 = (const float4*)(half ? vg : kg);
    for (int f = threadIdx.x; f < 8192; f += blockDim.x) {
      const int d = f & 31, s = (f >> 5) & 31, h = f >> 10;
      d4[dbase + (size_t)h * 1024 + s * 32 + d] =
          s4[(((size_t)b * SS + blk * 32 + s) * 8 + h) * 32 + d];
    }
  } else {
    const float4* s4 = (const float4*)cache_in;
    for (int f = threadIdx.x; f < 8192; f += blockDim.x)
      d4[dbase + f] = s4[dbase + f];
  }
}

// fallback (no workspace): copy + scatter
__global__ void cache_copy(const float* __restrict__ src, float* __restrict__ dst, int n4) {
  const float4* s = (const float4*)src;
  float4* d = (float4*)dst;
  for (int i = blockIdx.x * blockDim.x + threadIdx.x; i < n4; i += gridDim.x * blockDim.x)
    d[i] = s[i];
}
__global__ void cache_scatter(const float* __restrict__ kg, const float* __restrict__ vg,
                              const int* __restrict__ ids, float* __restrict__ cache) {
  const int slot = blockIdx.x;
  const int half = blockIdx.y;
  const int b = slot >> 6, blk = slot & 63;
  const int page = ids[slot];
  const float4* s4 = (const float4*)(half ? vg : kg);
  float4* d4 = (float4*)cache;
  for (int f = threadIdx.x; f < 8192; f += blockDim.x) {
    const int d = f & 31, s = (f >> 5) & 31, h = f >> 10;
    d4[(((size_t)page * 2 + half) * 8 + h) * 1024 + s * 32 + d] =
        s4[(((size_t)b * SS + blk * 32 + s) * 8 + h) * 32 + d];
  }
}

extern "C" void kernel_launch(void* const* d_in, const int* in_sizes, int n_in,
                              void* d_out, int out_size, void* d_ws, size_t ws_size,
                              hipStream_t stream) {
  const float* q = (const float*)d_in[0];
  const float* k = (const float*)d_in[1];
  const float* v = (const float*)d_in[2];
  const float* cache_in = (const float*)d_in[3];
  const int* ids = (const int*)d_in[4];
  const float* sink = (const float*)d_in[5];
  float* out = (float*)d_out;
  float* cache_out = out + (size_t)BB * SS * HQ * DD; // 16,777,216

  const int nslots = in_sizes[4];                       // B * nb = 128
  const int npages = in_sizes[3] / (2 * HKV * 32 * DD); // 128

  if (ws_size >= (size_t)npages * sizeof(int) && npages <= 1024) {
    int* inv = (int*)d_ws;
    build_inv<<<1, 1024, 0, stream>>>(ids, inv, npages, nslots);
    page_fill<<<dim3(npages, 2), 256, 0, stream>>>(k, v, cache_in, inv, cache_out);
  } else {
    cache_copy<<<4096, 256, 0, stream>>>(cache_in, cache_out, (BB * SS * HKV * DD * 2) / 4);
    cache_scatter<<<dim3(BB * 64, 2), 256, 0, stream>>>(k, v, ids, cache_out);
  }
  attn_kernel<<<512, 512, 0, stream>>>(q, k, v, sink, out);
}